// Round 10
// baseline (99.531 us; speedup 1.0000x reference)
//
#include <hip/hip_runtime.h>
#include <hip/hip_bf16.h>

// Single causal attention head. B=4, T=4096, C=1024, H=64, fp32 in/out.
// R9: flash = 1-wave blocks (64 thr), ZERO in-loop LDS / barriers.
// K A-frags direct-global double-buffered 1 tile ahead; V consumed as V^T
// (qkv writes v transposed), B-frags direct-global issued at iter start.
// Softmax/P-build (cvt_pk + permlane32_swap) carried over from R8 verified.
// Defer-max THR tightened 8->4 (absmax margin). qkv/wt kept from R6.

#define B_DIM 4
#define T_DIM 4096
#define C_DIM 1024
#define H_DIM 64
#define NBT   16384           // B*T
#define SCALE2 0.0450842066f  // log2(e)/32 : base-2 domain folded into q
#define KP 72                 // LDS stride for qkv staging

typedef __attribute__((ext_vector_type(8))) short bf8;      // 8 bf16
typedef __attribute__((ext_vector_type(4))) float f32x4;    // 16x16 acc
typedef __attribute__((ext_vector_type(16))) float f32x16;  // 32x32 acc

__device__ __forceinline__ float fast_exp2(float f) {
    return __builtin_amdgcn_exp2f(f);   // v_exp_f32 (base-2)
}
__device__ __forceinline__ ushort f2bf(float f) {
    union { float f; uint u; } x; x.f = f;
    const uint u = x.u;
    return (ushort)((u + 0x7FFFu + ((u >> 16) & 1u)) >> 16);  // RNE
}
__device__ __forceinline__ uint cvt_pk_bf16(float lo, float hi) {
    uint r;
    asm("v_cvt_pk_bf16_f32 %0, %1, %2" : "=v"(r) : "v"(lo), "v"(hi));
    return r;
}
__device__ __forceinline__ void permswapf(float& a, float& b) {
    asm volatile("v_permlane32_swap_b32 %0, %1" : "+v"(a), "+v"(b));
}
__device__ __forceinline__ void permswapu(uint& a, uint& b) {
    asm volatile("v_permlane32_swap_b32 %0, %1" : "+v"(a), "+v"(b));
}
__device__ __forceinline__ bf8 frag_from(uint w0, uint w1, uint w2, uint w3) {
    union { uint u[4]; bf8 f; } x;
    x.u[0] = w0; x.u[1] = w1; x.u[2] = w2; x.u[3] = w3;
    return x.f;
}

// ---------------------------------------------------------------------------
// W^T pre-pass: wtg[col][k], col 0..191 = (Wq|Wk|Wv) columns, bf16.
// ---------------------------------------------------------------------------
__global__ __launch_bounds__(256) void wt_kernel(
    const float* __restrict__ Wq, const float* __restrict__ Wk,
    const float* __restrict__ Wv, ushort* __restrict__ wtg)
{
    const int id  = blockIdx.x * 256 + threadIdx.x;  // 24576 total
    const int col = id >> 7;
    const int k8  = (id & 127) * 8;
    const int m   = col >> 6, lc = col & 63;
    const float* W = (m == 0) ? Wq : (m == 1) ? Wk : Wv;
    ushort o[8];
    #pragma unroll
    for (int i = 0; i < 8; ++i)
        o[i] = f2bf(W[(size_t)(k8 + i) * H_DIM + lc]);
    *(bf8*)&wtg[(size_t)col * C_DIM + k8] = *(bf8*)o;
}

// ---------------------------------------------------------------------------
// QKV projection (R6 structure). Block = 32 rows x 192 cols, 4 waves x 3
// col-subtiles; K-chunks of 64 with reg-prefetch. v written TRANSPOSED:
// vT[h][b*T + row]. Grid 512.
// ---------------------------------------------------------------------------
__global__ __launch_bounds__(256) void qkv_mfma_kernel(
    const float* __restrict__ x, const ushort* __restrict__ wtg,
    ushort* __restrict__ qo, ushort* __restrict__ ko, ushort* __restrict__ vT)
{
    __shared__ ushort xs[32][KP];
    __shared__ ushort wts[192][KP];
    const int t    = threadIdx.x;
    const int lane = t & 63, wave = t >> 6;
    const int g    = lane >> 4, lid = lane & 15;
    const size_t r0 = (size_t)blockIdx.x * 32;

    f32x4 acc[2][3] = {};

    const int xrow = t >> 3, xcol = (t & 7) * 8;   // x stage: 32x64
    float4 xr[2];
    bf8 wreg[6];

    xr[0] = *(const float4*)&x[(r0 + xrow) * C_DIM + xcol];
    xr[1] = *(const float4*)&x[(r0 + xrow) * C_DIM + xcol + 4];
    #pragma unroll
    for (int it = 0; it < 6; ++it) {
        const int n = t + it * 256;
        wreg[it] = *(const bf8*)&wtg[(size_t)(n >> 3) * C_DIM + (n & 7) * 8];
    }

    for (int kc = 0; kc < C_DIM / 64; ++kc) {
        __syncthreads();
        {
            uint p[4];
            p[0] = cvt_pk_bf16(xr[0].x, xr[0].y); p[1] = cvt_pk_bf16(xr[0].z, xr[0].w);
            p[2] = cvt_pk_bf16(xr[1].x, xr[1].y); p[3] = cvt_pk_bf16(xr[1].z, xr[1].w);
            *(bf8*)&xs[xrow][xcol] = *(bf8*)p;
            #pragma unroll
            for (int it = 0; it < 6; ++it) {
                const int n = t + it * 256;
                *(bf8*)&wts[n >> 3][(n & 7) * 8] = wreg[it];
            }
        }
        __syncthreads();
        if (kc + 1 < C_DIM / 64) {
            const int kb = (kc + 1) * 64;
            xr[0] = *(const float4*)&x[(r0 + xrow) * C_DIM + kb + xcol];
            xr[1] = *(const float4*)&x[(r0 + xrow) * C_DIM + kb + xcol + 4];
            #pragma unroll
            for (int it = 0; it < 6; ++it) {
                const int n = t + it * 256;
                wreg[it] = *(const bf8*)&wtg[(size_t)(n >> 3) * C_DIM + kb + (n & 7) * 8];
            }
        }
        #pragma unroll
        for (int ks = 0; ks < 2; ++ks) {
            const bf8 a0 = *(const bf8*)&xs[lid][ks * 32 + g * 8];
            const bf8 a1 = *(const bf8*)&xs[16 + lid][ks * 32 + g * 8];
            #pragma unroll
            for (int j = 0; j < 3; ++j) {
                const int ct = wave * 3 + j;
                const bf8 bb = *(const bf8*)&wts[ct * 16 + lid][ks * 32 + g * 8];
                acc[0][j] = __builtin_amdgcn_mfma_f32_16x16x32_bf16(a0, bb, acc[0][j], 0, 0, 0);
                acc[1][j] = __builtin_amdgcn_mfma_f32_16x16x32_bf16(a1, bb, acc[1][j], 0, 0, 0);
            }
        }
    }

    // epilogue: C map col=lid, row=4g+r. q scaled by SCALE2; v transposed.
    #pragma unroll
    for (int rt = 0; rt < 2; ++rt)
        #pragma unroll
        for (int j = 0; j < 3; ++j) {
            const int ct = wave * 3 + j;
            const int m  = ct >> 2, lc = (ct & 3) * 16 + lid;
            if (m == 2) {   // vT[lc][r0 + rt*16 + 4g .. +3]  (8B packed store)
                ushort4 o;
                o.x = f2bf(acc[rt][j][0]); o.y = f2bf(acc[rt][j][1]);
                o.z = f2bf(acc[rt][j][2]); o.w = f2bf(acc[rt][j][3]);
                *(ushort4*)&vT[(size_t)lc * NBT + r0 + rt * 16 + 4 * g] = o;
            } else {
                ushort* dst = (m == 0) ? qo : ko;
                const float sc = (m == 0) ? SCALE2 : 1.f;
                #pragma unroll
                for (int r = 0; r < 4; ++r) {
                    const size_t row = r0 + rt * 16 + 4 * g + r;
                    dst[row * H_DIM + lc] = f2bf(acc[rt][j][r] * sc);
                }
            }
        }
}

// ---------------------------------------------------------------------------
// Split-K flash: 1 wave/block, QBLK=32, KBLK=64, NO in-loop LDS/barriers.
// K A-frags direct-global (double-buffered 1 tile ahead); V^T B-frags
// direct-global (issued at iter start). Grid (nslots, 128, 4), 64 threads.
// ---------------------------------------------------------------------------
__global__ __launch_bounds__(64) void flash_mfma_kernel(
    const ushort* __restrict__ q, const ushort* __restrict__ k,
    const ushort* __restrict__ vT, float* __restrict__ pO,
    float* __restrict__ pm, float* __restrict__ pl,
    float* __restrict__ out, int S, int nslots, int direct)
{
    const int qt  = 127 - blockIdx.y;        // heavy q-tiles first
    const int c   = blockIdx.x;
    const int ntk = (qt >> 1) + 1;           // 64-key tiles needed
    const int kb  = c * S;
    const int ke  = min((c + 1) * S, ntk);
    if (kb >= ke) return;

    __shared__ float fsh[32];                // rescale broadcast (1 wave)
    __shared__ float lsh[32];                // l broadcast (epilogue)

    const int lane = threadIdx.x;
    const int l31  = lane & 31, hi = lane >> 5;
    const int b    = blockIdx.z;
    const int qrow0 = qt * 32;
    const size_t base = (size_t)b * T_DIM * H_DIM;
    const ushort* vTb = vT + (size_t)b * T_DIM;   // vT[h][b*T + key]

    // Q B-frags (log2-scaled): lane holds Q2[qrow0+l31][kk*16+hi*8 ..)
    bf8 qf[4];
    {
        const size_t qoff = base + (size_t)(qrow0 + l31) * H_DIM + hi * 8;
        #pragma unroll
        for (int kk = 0; kk < 4; ++kk)
            qf[kk] = *(const bf8*)&q[qoff + kk * 16];
    }

    f32x16 oa0 = {}, oa1 = {};           // O[q row regs][h = l31 / 32+l31]
    float m_run = -1e29f, l_run = 0.f;   // per-lane, q = qrow0 + l31 (log2)

    bf8 kA0[4], kA1[4], kB0[4], kB1[4];  // K frag double buffer
    bf8 vb0[4], vb1[4];                  // V^T frags (single buffer)

    #define LOADK(K0, K1, kt_) do {                                          \
        const size_t ko_ = base + ((size_t)((kt_) * 64 + l31)) * H_DIM + hi * 8; \
        _Pragma("unroll")                                                    \
        for (int kk = 0; kk < 4; ++kk) {                                     \
            K0[kk] = *(const bf8*)&k[ko_ + kk * 16];                         \
            K1[kk] = *(const bf8*)&k[ko_ + 32 * H_DIM + kk * 16];            \
        } } while (0)

    #define LOADV(kt_) do {                                                  \
        const size_t vo_ = (size_t)l31 * NBT + (kt_) * 64 + hi * 8;          \
        _Pragma("unroll")                                                    \
        for (int kk = 0; kk < 4; ++kk) {                                     \
            vb0[kk] = *(const bf8*)&vTb[vo_ + kk * 16];                      \
            vb1[kk] = *(const bf8*)&vTb[vo_ + (size_t)32 * NBT + kk * 16];   \
        } } while (0)

    #define BUILD_PA(dst, sv, bofs) do {                                     \
        uint a0_ = cvt_pk_bf16(sv[(bofs)+0], sv[(bofs)+1]);                  \
        uint b0_ = cvt_pk_bf16(sv[(bofs)+4], sv[(bofs)+5]);                  \
        uint a1_ = cvt_pk_bf16(sv[(bofs)+2], sv[(bofs)+3]);                  \
        uint b1_ = cvt_pk_bf16(sv[(bofs)+6], sv[(bofs)+7]);                  \
        permswapu(a0_, b0_); permswapu(a1_, b1_);                            \
        dst = frag_from(a0_, a1_, b0_, b1_);                                 \
    } while (0)

    #define COMPUTE_TILE(K0, K1, kt_) do {                                   \
        f32x16 st0 = {}, st1 = {};                                           \
        _Pragma("unroll")                                                    \
        for (int kk = 0; kk < 4; ++kk)                                       \
            st0 = __builtin_amdgcn_mfma_f32_32x32x16_bf16(K0[kk], qf[kk], st0, 0, 0, 0); \
        _Pragma("unroll")                                                    \
        for (int kk = 0; kk < 4; ++kk)                                       \
            st1 = __builtin_amdgcn_mfma_f32_32x32x16_bf16(K1[kk], qf[kk], st1, 0, 0, 0); \
        if ((kt_) == ntk - 1) {   /* causal mask, diagonal tile only */      \
            const int qg  = qrow0 + l31;                                     \
            const int kb0 = (kt_) * 64 + 4 * hi;                             \
            _Pragma("unroll")                                                \
            for (int r = 0; r < 16; ++r) {                                   \
                const int key0 = kb0 + (r & 3) + 8 * (r >> 2);               \
                if (key0 > qg)      st0[r] = -1e30f;                         \
                if (key0 + 32 > qg) st1[r] = -1e30f;                         \
            }                                                                \
        }                                                                    \
        float mx = st0[0];                                                   \
        _Pragma("unroll")                                                    \
        for (int r = 1; r < 16; ++r) mx = fmaxf(mx, st0[r]);                 \
        _Pragma("unroll")                                                    \
        for (int r = 0; r < 16; ++r) mx = fmaxf(mx, st1[r]);                 \
        { float ma = mx, mb = mx; permswapf(ma, mb); mx = fmaxf(ma, mb); }   \
        const bool nof = (mx <= m_run + 4.0f);   /* defer-max THR=4 */       \
        const float mnew = nof ? m_run : mx;                                 \
        const float fsc  = nof ? 1.0f : fast_exp2(m_run - mnew);             \
        m_run = mnew;                                                        \
        float ls = 0.f;                                                      \
        _Pragma("unroll")                                                    \
        for (int r = 0; r < 16; ++r) { st0[r] = fast_exp2(st0[r] - mnew); ls += st0[r]; } \
        _Pragma("unroll")                                                    \
        for (int r = 0; r < 16; ++r) { st1[r] = fast_exp2(st1[r] - mnew); ls += st1[r]; } \
        { float la = ls, lb = ls; permswapf(la, lb); ls = la + lb; }         \
        l_run = l_run * fsc + ls;                                            \
        bf8 pa[4];                                                           \
        BUILD_PA(pa[0], st0, 0);                                             \
        BUILD_PA(pa[1], st0, 8);                                             \
        BUILD_PA(pa[2], st1, 0);                                             \
        BUILD_PA(pa[3], st1, 8);                                             \
        if (!__all(nof)) {                                                   \
            if (lane < 32) fsh[l31] = fsc;                                   \
            _Pragma("unroll")                                                \
            for (int j = 0; j < 4; ++j) {                                    \
                const float4 fb = *(const float4*)&fsh[8 * j + 4 * hi];      \
                oa0[4*j+0] *= fb.x; oa0[4*j+1] *= fb.y;                      \
                oa0[4*j+2] *= fb.z; oa0[4*j+3] *= fb.w;                      \
                oa1[4*j+0] *= fb.x; oa1[4*j+1] *= fb.y;                      \
                oa1[4*j+2] *= fb.z; oa1[4*j+3] *= fb.w;                      \
            }                                                                \
        }                                                                    \
        _Pragma("unroll")                                                    \
        for (int kk = 0; kk < 4; ++kk) {                                     \
            oa0 = __builtin_amdgcn_mfma_f32_32x32x16_bf16(pa[kk], vb0[kk], oa0, 0, 0, 0); \
            oa1 = __builtin_amdgcn_mfma_f32_32x32x16_bf16(pa[kk], vb1[kk], oa1, 0, 0, 0); \
        }                                                                    \
    } while (0)

    // main loop: 2x unrolled ping-pong on K buffers, no barriers anywhere
    LOADK(kA0, kA1, kb);
    int kt = kb;
    for (;;) {
        LOADV(kt);                            // V issued early (QK+softmax cover)
        if (kt + 1 < ke) LOADK(kB0, kB1, kt + 1);
        COMPUTE_TILE(kA0, kA1, kt);
        ++kt; if (kt >= ke) break;
        LOADV(kt);
        if (kt + 1 < ke) LOADK(kA0, kA1, kt + 1);
        COMPUTE_TILE(kB0, kB1, kt);
        ++kt; if (kt >= ke) break;
    }
    #undef COMPUTE_TILE
    #undef BUILD_PA
    #undef LOADV
    #undef LOADK

    if (direct) {
        if (lane < 32) lsh[l31] = l_run;
        #pragma unroll
        for (int j = 0; j < 4; ++j) {
            const float4 lv = *(const float4*)&lsh[8 * j + 4 * hi];
            const float iv[4] = {1.f / lv.x, 1.f / lv.y, 1.f / lv.z, 1.f / lv.w};
            #pragma unroll
            for (int rr = 0; rr < 4; ++rr) {
                const size_t rowoff = base + (size_t)(qrow0 + 8 * j + 4 * hi + rr) * H_DIM;
                out[rowoff + l31]      = oa0[4 * j + rr] * iv[rr];
                out[rowoff + 32 + l31] = oa1[4 * j + rr] * iv[rr];
            }
        }
    } else {
        const size_t u = ((size_t)b * 128 + qt) * nslots + c;
        float* po = pO + u * 2048;
        #pragma unroll
        for (int j = 0; j < 4; ++j)
            #pragma unroll
            for (int rr = 0; rr < 4; ++rr) {
                const int row = 8 * j + 4 * hi + rr;
                po[(size_t)row * 64 + l31]      = oa0[4 * j + rr];
                po[(size_t)row * 64 + 32 + l31] = oa1[4 * j + rr];
            }
        if (lane < 32) {
            pm[u * 32 + l31] = m_run;   // log2 domain
            pl[u * 32 + l31] = l_run;
        }
    }
}

// ---------------------------------------------------------------------------
// Combine partials (log2 domain), 32-row q-tiles. Grid (128, 4).
// ---------------------------------------------------------------------------
__global__ __launch_bounds__(256) void combine_kernel(
    const float* __restrict__ pO, const float* __restrict__ pm,
    const float* __restrict__ pl, float* __restrict__ out,
    int S, int nslots)
{
    const int qt = blockIdx.x, b = blockIdx.y;
    const int ntk = (qt >> 1) + 1;
    const int nch = (ntk + S - 1) / S;
    const int t = threadIdx.x;
    const int row = t >> 3, seg = (t & 7) * 8;
    const size_t u0 = ((size_t)b * 128 + qt) * nslots;

    float M = -1e30f;
    for (int cc = 0; cc < nch; ++cc)
        M = fmaxf(M, pm[(u0 + cc) * 32 + row]);
    float L = 0.f, alpha[8];
    for (int cc = 0; cc < nch; ++cc) {
        alpha[cc] = fast_exp2(pm[(u0 + cc) * 32 + row] - M);
        L += pl[(u0 + cc) * 32 + row] * alpha[cc];
    }
    const float inv = 1.f / L;

    float4 o[2] = {};
    for (int cc = 0; cc < nch; ++cc) {
        const float a = alpha[cc];
        #pragma unroll
        for (int j = 0; j < 2; ++j) {
            const float4 p = *(const float4*)&pO[(u0 + cc) * 2048 +
                                                 (size_t)row * 64 + seg + j * 4];
            o[j].x += p.x * a; o[j].y += p.y * a;
            o[j].z += p.z * a; o[j].w += p.w * a;
        }
    }
    const size_t ob = (size_t)b * T_DIM * H_DIM + (size_t)(qt * 32 + row) * H_DIM + seg;
    #pragma unroll
    for (int j = 0; j < 2; ++j) {
        float4 r;
        r.x = o[j].x * inv; r.y = o[j].y * inv;
        r.z = o[j].z * inv; r.w = o[j].w * inv;
        *(float4*)&out[ob + j * 4] = r;
    }
}

// ---------------------------------------------------------------------------
extern "C" void kernel_launch(void* const* d_in, const int* in_sizes, int n_in,
                              void* d_out, int out_size, void* d_ws, size_t ws_size,
                              hipStream_t stream)
{
    const float* x  = (const float*)d_in[0];
    const float* Wq = (const float*)d_in[1];
    const float* Wk = (const float*)d_in[2];
    const float* Wv = (const float*)d_in[3];
    float* out = (float*)d_out;

    const size_t MB = 1u << 20;
    char* ws = (char*)d_ws;
    ushort* qb  = (ushort*)(ws);            // 2MB
    ushort* kb  = (ushort*)(ws + 2 * MB);   // 2MB
    ushort* vTb = (ushort*)(ws + 4 * MB);   // 2MB, transposed [64][16384]
    ushort* wtg = (ushort*)(ws + 6 * MB);   // 384KB
    float*  pO  = (float*)(ws + 7 * MB);    // nslots*4MB

    int nslots, S;
    if      (ws_size >= 41 * MB) { nslots = 8; S = 8;  }
    else if (ws_size >= 24 * MB) { nslots = 4; S = 16; }
    else if (ws_size >= 16 * MB) { nslots = 2; S = 32; }
    else                         { nslots = 1; S = 64; }
    const int direct = (nslots == 1);
    float* pm = pO + (size_t)nslots * 1048576;  // nslots*64KB
    float* pl = pm + (size_t)nslots * 16384;

    hipLaunchKernelGGL(wt_kernel, dim3(96), dim3(256), 0, stream, Wq, Wk, Wv, wtg);
    hipLaunchKernelGGL(qkv_mfma_kernel, dim3((B_DIM * T_DIM) / 32), dim3(256),
                       0, stream, x, wtg, qb, kb, vTb);
    hipLaunchKernelGGL(flash_mfma_kernel, dim3(nslots, T_DIM / 32, B_DIM), dim3(64),
                       0, stream, qb, kb, vTb, pO, pm, pl, out, S, nslots, direct);
    if (!direct)
        hipLaunchKernelGGL(combine_kernel, dim3(T_DIM / 32, B_DIM), dim3(256),
                           0, stream, pO, pm, pl, out, S, nslots);
}